// Round 9
// baseline (537.494 us; speedup 1.0000x reference)
//
#include <hip/hip_runtime.h>
#include <cstdint>
#include <cstddef>

#define RANK_K 819            // kth = sorted[819] (820th smallest of 2048)
// conv: x[64,3,32,32] * w[2048,3,6,6] VALID -> [64,2048,27,27]

typedef __attribute__((ext_vector_type(2))) float f32x2;

// packed f32 FMA: two independent IEEE fma ops (lo,hi) in one instruction.
// Each half is a separate single-rounding fma -> per-output chain unchanged.
__device__ __forceinline__ f32x2 pk_fma(f32x2 a, f32x2 b, f32x2 c) {
  f32x2 d;
  asm("v_pk_fma_f32 %0, %1, %2, %3" : "=v"(d) : "v"(a), "v"(b), "v"(c));
  return d;
}

__device__ __forceinline__ int zbin256(float z) {
  // 256 bins over [-8,8), width 1/16. Monotone partition; selection is exact
  // rank within bin, so binning never affects the kth VALUE.
  float t = (z + 8.0f) * 16.0f;
  t = t < 0.0f ? 0.0f : (t > 255.0f ? 255.0f : t);
  return (int)t;
}

// ------- kernel 1: weight transpose w[c][ic][ky][kx] -> wt[(ky,kx,ic)][c] ---
__global__ __launch_bounds__(256) void net99_wtrans(const float* __restrict__ w,
                                                    float* __restrict__ wt) {
  int idx = blockIdx.x * 256 + threadIdx.x;
  if (idx < 2048 * 108) {
    int kk = idx / 2048, c = idx % 2048;
    int ic = kk % 3, sp = kk / 3, ky = sp / 6, kx = sp % 6;
    wt[idx] = w[c * 108 + ic * 36 + ky * 6 + kx];   // coalesced write
  }
}

// ------- kernel 2: f32 conv via v_pk_fma_f32, chain order (ky,kx,ic) --------
// Pair tile xp is pinned into VGPRs via keep-alive asm (compiler was sinking
// the LDS loads to each use -> 6x re-reads, round-8 post-mortem). Bit-exact.
__global__ __launch_bounds__(256, 2) void net99_conv(const float* __restrict__ x,
                                                     const float* __restrict__ wt,
                                                     float* __restrict__ conv, int b0) {
  const int y  = blockIdx.x;       // 0..26
  const int ct = blockIdx.y;       // 0..7 (channel tile of 256)
  const int bl = blockIdx.z;       // local batch
  const int b  = b0 + bl;
  const int tid = threadIdx.x;
  __shared__ float xs[3][6][32];
  __shared__ f32x2 xs2[3][6][19];  // pair m = (row[m], row[m+13]), m=0..18
  for (int i = tid; i < 576; i += 256) {
    int ic = i / 192, rem = i % 192, r = rem / 32, col = rem % 32;
    xs[ic][r][col] = x[((b * 3 + ic) * 32 + (y + r)) * 32 + col];
  }
  __syncthreads();
  for (int i = tid; i < 342; i += 256) {
    int ic = i / 114, rem = i % 114, r = rem / 19, m = rem % 19;
    f32x2 t; t.x = xs[ic][r][m]; t.y = xs[ic][r][m + 13];
    xs2[ic][r][m] = t;
  }
  __syncthreads();
  const int c = ct * 256 + tid;
  const float* wtc = wt + c;
  f32x2 acc2[13];
  float acc26 = 0.0f;
#pragma unroll
  for (int j = 0; j < 13; ++j) acc2[j] = (f32x2)(0.0f);
#pragma unroll 1
  for (int ky = 0; ky < 6; ++ky) {   // runtime loop: bounds register pressure
    f32x2 xp[3][19];
#pragma unroll
    for (int ic = 0; ic < 3; ++ic)
#pragma unroll
      for (int m = 0; m < 19; ++m) xp[ic][m] = xs2[ic][ky][m];
    // pin the whole pair tile in VGPRs: loads happen exactly once per ky
#pragma unroll
    for (int ic = 0; ic < 3; ++ic)
#pragma unroll
      for (int m = 0; m < 19; ++m) asm volatile("" : "+v"(xp[ic][m]));
#pragma unroll
    for (int kx = 0; kx < 6; ++kx) {
#pragma unroll
      for (int ic = 0; ic < 3; ++ic) {
        float wv = wtc[(size_t)((ky * 6 + kx) * 3 + ic) * 2048];
        f32x2 wvv; wvv.x = wv; wvv.y = wv;
#pragma unroll
        for (int j = 0; j < 13; ++j)
          acc2[j] = pk_fma(wvv, xp[ic][kx + j], acc2[j]);   // outputs j, j+13
        acc26 = fmaf(wv, xp[ic][kx + 13].y, acc26);          // output 26
      }
    }
  }
  float* dst = conv + ((size_t)(bl * 27 + y) * 27) * 2048 + c;
#pragma unroll
  for (int j = 0; j < 13; ++j) {
    dst[(size_t)j * 2048]        = acc2[j].x;
    dst[(size_t)(j + 13) * 2048] = acc2[j].y;
  }
  dst[(size_t)26 * 2048] = acc26;
}

// ------- kernel 3: 4-pixel register-resident rank-819 select + byte mask ----
// Block handles pixels 4g..4g+3 -> 8 streams (pixel x branch). Wave w owns
// streams w and w+4 (2 reps) in scan+rank. Thread t owns channels 8t..8t+7.
__global__ __launch_bounds__(256, 2) void net99_select(const float* __restrict__ conv,
                                                       const float* __restrict__ bias,
                                                       uint8_t* __restrict__ mskb, int b0) {
  const int bl = blockIdx.x / 183;
  const int g  = blockIdx.x % 183;
  const int p0 = 4 * g;
  const int npix = (g < 182) ? 4 : 1;     // 182*4=728, tail block: pixel 728
  const int nst  = 2 * npix;
  const int gb = b0 + bl;
  const int tid  = threadIdx.x;
  const int lane = tid & 63;
  const int wid  = tid >> 6;
  __shared__ uint32_t hist[8][256];       //  8 KB
  __shared__ float    cand[8][512];       // 16 KB
  __shared__ int      cnt[8];
  __shared__ int      sbin[8], sbelow[8];
  __shared__ float    skth[8];

  const float4* __restrict__ s0 =
      (const float4*)(conv + ((size_t)bl * 729 + p0) * 2048) + tid * 2;
  const float4* __restrict__ b4 = (const float4*)bias + tid * 2;
  float4 va[4][2];
#pragma unroll
  for (int k = 0; k < 4; ++k) {
    if (k < npix) { va[k][0] = s0[k * 512]; va[k][1] = s0[k * 512 + 1]; }
    else          { va[k][0] = float4{0,0,0,0}; va[k][1] = float4{0,0,0,0}; }
  }
  float4 ba = b4[0], bb = b4[1];

#pragma unroll
  for (int r = 0; r < 8; ++r) (&hist[0][0])[tid + 256 * r] = 0u;
  if (tid < 8) cnt[tid] = 0;

  float z[8][8];
  {
    float bv[8] = {ba.x, ba.y, ba.z, ba.w, bb.x, bb.y, bb.z, bb.w};
#pragma unroll
    for (int k = 0; k < 4; ++k) {
      float v[8] = {va[k][0].x, va[k][0].y, va[k][0].z, va[k][0].w,
                    va[k][1].x, va[k][1].y, va[k][1].z, va[k][1].w};
#pragma unroll
      for (int j = 0; j < 8; ++j) {
        z[2 * k][j]     = bv[j] - v[j];   // single f32 op, matches reference
        z[2 * k + 1][j] = bv[j] + v[j];
      }
    }
  }
  __syncthreads();                                  // hist zeros visible
#pragma unroll
  for (int s = 0; s < 8; ++s) {
    if (s < nst) {
#pragma unroll
      for (int j = 0; j < 8; ++j) atomicAdd(&hist[s][zbin256(z[s][j])], 1u);
    }
  }
  __syncthreads();
#pragma unroll
  for (int rep = 0; rep < 2; ++rep) {     // wave w scans streams w, w+4
    const int s = wid + 4 * rep;
    if (s < nst) {
      int h[4];
#pragma unroll
      for (int t = 0; t < 4; ++t) h[t] = (int)hist[s][lane * 4 + t];
      int loc = h[0] + h[1] + h[2] + h[3];
      int inc = loc;
#pragma unroll
      for (int off = 1; off < 64; off <<= 1) {
        int u = __shfl_up(inc, off);
        if (lane >= off) inc += u;
      }
      int pre = inc - loc;
      if (pre <= RANK_K && RANK_K < pre + loc) {    // exactly one lane
        int cum = pre;
#pragma unroll
        for (int t = 0; t < 4; ++t) {
          if (RANK_K < cum + h[t]) { sbin[s] = lane * 4 + t; sbelow[s] = cum; break; }
          cum += h[t];
        }
      }
    }
  }
  __syncthreads();
#pragma unroll
  for (int s = 0; s < 8; ++s) {                     // compact from registers
    if (s < nst) {
      const int tb = sbin[s];
#pragma unroll
      for (int j = 0; j < 8; ++j) {
        if (zbin256(z[s][j]) == tb) {
          int u = atomicAdd(&cnt[s], 1);
          if (u < 512) cand[s][u] = z[s][j];
        }
      }
    }
  }
  __syncthreads();
#pragma unroll
  for (int rep = 0; rep < 2; ++rep) {     // exact rank, wave w: streams w, w+4
    const int s = wid + 4 * rep;
    if (s < nst) {
      int cN = cnt[s] < 512 ? cnt[s] : 512;
      int rloc = RANK_K - sbelow[s];
      for (int ci = lane; ci < cN; ci += 64) {
        float v = cand[s][ci]; int rk = 0;
        for (int j = 0; j < cN; ++j) {
          float u = cand[s][j];
          rk += (u < v) || (u == v && j < ci);
        }
        if (rk == rloc) skth[s] = v;                // unique winning VALUE
      }
    }
  }
  __syncthreads();
#pragma unroll
  for (int k = 0; k < 4; ++k) {
    if (k < npix) {
      uint32_t m0 = 0u, m1 = 0u;
      const float k0 = skth[2 * k], k1 = skth[2 * k + 1];
#pragma unroll
      for (int j = 0; j < 8; ++j) {
        m0 |= (uint32_t)(z[2 * k][j] < k0) << j;
        m1 |= (uint32_t)(z[2 * k + 1][j] < k1) << j;
      }
      const size_t pix = (size_t)gb * 729 + p0 + k;
      mskb[pix * 256 + tid]                      = (uint8_t)m0;
      mskb[((size_t)64 * 729 + pix) * 256 + tid] = (uint8_t)m1;
    }
  }
}

// ------- kernel 4: bit-exact avg_pool(5,3,ceil) + adaptive(6), LDS-staged ---
__global__ __launch_bounds__(256) void net99_pool(const uint32_t* __restrict__ msk,
                                                  float* __restrict__ out) {
  __shared__ uint32_t stage[729 * 8];   // 23,328 B: full (s,b,cg) mask slice
  const int blk = blockIdx.x;           // 0..1023 = (sb, cg)
  const int cg  = blk & 7;
  const int sb  = blk >> 3;             // s*64 + b
  const int tid = threadIdx.x;
  const uint32_t* src = msk + (size_t)sb * 729 * 64 + cg * 8;
  for (int i = tid; i < 729 * 8; i += 256) {
    int p = i >> 3, w = i & 7;
    stage[i] = src[(size_t)p * 64 + w];
  }
  __syncthreads();
  const int lw = tid >> 5, sel = tid & 31;
  uint32_t rbm[27];
  for (int y = 0; y < 27; ++y) {
    uint32_t rb = 0;
#pragma unroll
    for (int xx = 0; xx < 27; ++xx)
      rb |= ((stage[(y * 27 + xx) * 8 + lw] >> sel) & 1u) << xx;
    rbm[y] = rb;
  }
  constexpr uint32_t WM[9] = {0x1Fu, 0xF8u, 0x7C0u, 0x3E00u, 0x1F000u,
                              0xF8000u, 0x7C0000u, 0x3E00000u, 0x7000000u};
  constexpr int CC[9]  = {5, 5, 5, 5, 5, 5, 5, 5, 3};
  constexpr int BW0[6] = {0, 1, 3, 4, 6, 7};
  constexpr int BW1[6] = {1, 2, 4, 5, 7, 8};
  const int s = sb >> 6, b = sb & 63, c = cg * 256 + tid;
  float* dst = out + (size_t)s * 4718592 + (size_t)(b * 2048 + c) * 36;
  for (int i = 0; i < 6; ++i) {
    float P[2][9];
#pragma unroll
    for (int t = 0; t < 2; ++t) {
      int r  = t ? BW1[i] : BW0[i];
      int y0 = 3 * r;
      int y1 = (y0 + 5 > 27) ? 27 : y0 + 5;
      int cr = y1 - y0;
      int pp[9];
#pragma unroll
      for (int cx = 0; cx < 9; ++cx) pp[cx] = 0;
      for (int yy = y0; yy < y1; ++yy) {
        uint32_t rb = rbm[yy];
#pragma unroll
        for (int cx = 0; cx < 9; ++cx) pp[cx] += __popc(rb & WM[cx]);
      }
#pragma unroll
      for (int cx = 0; cx < 9; ++cx)
        P[t][cx] = (float)pp[cx] / (float)(cr * CC[cx]);   // IEEE f32 div
    }
    float M[9];
#pragma unroll
    for (int cx = 0; cx < 9; ++cx) M[cx] = (P[0][cx] + P[1][cx]) * 0.5f;
#pragma unroll
    for (int j = 0; j < 6; ++j)
      dst[i * 6 + j] = (M[BW0[j]] + M[BW1[j]]) * 0.5f;
  }
}

extern "C" void kernel_launch(void* const* d_in, const int* in_sizes, int n_in,
                              void* d_out, int out_size, void* d_ws, size_t ws_size,
                              hipStream_t stream) {
  const float* x    = (const float*)d_in[0];
  const float* w    = (const float*)d_in[1];
  const float* bias = (const float*)d_in[2];
  float* out = (float*)d_out;
  uint8_t* ws = (uint8_t*)d_ws;

  const size_t WT_BYTES   = (size_t)108 * 2048 * 4;          //   884,736
  const size_t MASK_OFF   = WT_BYTES;
  const size_t MASK_BYTES = (size_t)2 * 64 * 729 * 64 * 4;   // 23,887,872
  const size_t CONV_OFF   = MASK_OFF + MASK_BYTES;           // 24,772,608
  const size_t PER_B      = (size_t)2048 * 729 * 4;          // 5,971,968 per batch

  float*    wt   = (float*)ws;
  uint8_t*  mskb = (uint8_t*)(ws + MASK_OFF);
  uint32_t* msk  = (uint32_t*)(ws + MASK_OFF);
  float*    conv = (float*)(ws + CONV_OFF);

  size_t avail = ws_size > CONV_OFF ? ws_size - CONV_OFF : 0;
  int Bc = (int)(avail / PER_B);
  if (Bc < 1) Bc = 1;       // assumes ws_size >= ~31 MB
  if (Bc > 64) Bc = 64;

  hipLaunchKernelGGL(net99_wtrans, dim3((2048 * 108 + 255) / 256), dim3(256), 0, stream, w, wt);
  for (int b0 = 0; b0 < 64; b0 += Bc) {
    int nb = (64 - b0 < Bc) ? (64 - b0) : Bc;
    hipLaunchKernelGGL(net99_conv, dim3(27, 8, nb), dim3(256), 0, stream, x, wt, conv, b0);
    hipLaunchKernelGGL(net99_select, dim3(nb * 183), dim3(256), 0, stream, conv, bias, mskb, b0);
  }
  hipLaunchKernelGGL(net99_pool, dim3(1024), dim3(256), 0, stream, msk, out);
}

// Round 10
// 482.658 us; speedup vs baseline: 1.1136x; 1.1136x over previous
//
#include <hip/hip_runtime.h>
#include <cstdint>
#include <cstddef>

#define RANK_K 819            // kth = sorted[819] (820th smallest of 2048)
// conv: x[64,3,32,32] * w[2048,3,6,6] VALID -> [64,2048,27,27]

typedef __attribute__((ext_vector_type(2))) float f32x2;

// v_pk_fma_f32 with scalar-broadcast B operand from an SGPR pair holding
// (x_even, x_odd). Each half is an independent IEEE single-rounding fma.
// blo: both result halves read the LO dword of src1 (even column).
__device__ __forceinline__ f32x2 pk_fma_blo(f32x2 a, f32x2 bs, f32x2 c) {
  f32x2 d;
  asm("v_pk_fma_f32 %0, %1, %2, %3 op_sel_hi:[1,0,1]"
      : "=v"(d) : "v"(a), "s"(bs), "v"(c));
  return d;
}
// bhi: both result halves read the HI dword of src1 (odd column).
__device__ __forceinline__ f32x2 pk_fma_bhi(f32x2 a, f32x2 bs, f32x2 c) {
  f32x2 d;
  asm("v_pk_fma_f32 %0, %1, %2, %3 op_sel:[0,1,0] op_sel_hi:[1,1,1]"
      : "=v"(d) : "v"(a), "s"(bs), "v"(c));
  return d;
}

#define RFL(v) __int_as_float(__builtin_amdgcn_readfirstlane(__float_as_int(v)))

__device__ __forceinline__ int zbin256(float z) {
  // 256 bins over [-8,8), width 1/16. Monotone partition; selection is exact
  // rank within bin, so binning never affects the kth VALUE.
  float t = (z + 8.0f) * 16.0f;
  t = t < 0.0f ? 0.0f : (t > 255.0f ? 255.0f : t);
  return (int)t;
}

// ------- kernel 1: weight pairs wt4[k][cc] = (w[cc][k], w[cc+1024][k]) ------
// k-order = (ky*6+kx)*3+ic. Lane-consecutive cc -> coalesced 8B loads in conv.
__global__ __launch_bounds__(256) void net99_wtrans(const float* __restrict__ w,
                                                    f32x2* __restrict__ wt4) {
  int idx = blockIdx.x * 256 + threadIdx.x;
  if (idx < 108 * 1024) {
    int k = idx / 1024, cc = idx % 1024;
    int ic = k % 3, sp = k / 3, ky = sp / 6, kx = sp % 6;
    int wo = ic * 36 + ky * 6 + kx;
    f32x2 t;
    t.x = w[cc * 108 + wo];
    t.y = w[(cc + 1024) * 108 + wo];
    wt4[idx] = t;
  }
}

// ------- kernel 2: f32 conv, channel-paired pk_fma, x in SGPRs --------------
// Thread owns channels cpair and cpair+1024. x window is block-uniform ->
// staged to LDS once, then readfirstlane'd into SGPR pairs per ky. Chain
// order per output (ky->kx->ic ascending) identical to the verified kernel.
__global__ __launch_bounds__(256) void net99_conv(const float* __restrict__ x,
                                                  const f32x2* __restrict__ wt4,
                                                  float* __restrict__ conv, int b0) {
  const int y  = blockIdx.x;       // 0..26
  const int ct = blockIdx.y;       // 0..3 (512-channel tiles)
  const int bl = blockIdx.z;       // local batch
  const int b  = b0 + bl;
  const int tid = threadIdx.x;
  __shared__ __align__(16) float xs[3][6][32];
  for (int i = tid; i < 576; i += 256) {
    int ic = i / 192, rem = i % 192, r = rem / 32, col = rem % 32;
    xs[ic][r][col] = x[((b * 3 + ic) * 32 + (y + r)) * 32 + col];
  }
  __syncthreads();
  const int cpair = ct * 256 + tid;            // channels cpair, cpair+1024
  const f32x2* wtc = wt4 + cpair;
  f32x2 acc[27];
#pragma unroll
  for (int q = 0; q < 27; ++q) acc[q] = (f32x2)(0.0f);
#pragma unroll 1
  for (int ky = 0; ky < 6; ++ky) {   // runtime loop: code size + reg pressure
    // stage this ky's x rows into SGPR pairs: xpair[ic][m] = (x[2m], x[2m+1])
    f32x2 xpair[3][16];
#pragma unroll
    for (int ic = 0; ic < 3; ++ic) {
      const float4* rp = (const float4*)(&xs[ic][ky][0]);
#pragma unroll
      for (int j = 0; j < 8; ++j) {
        float4 f = rp[j];                       // uniform addr -> broadcast
        f32x2 plo, phi;
        plo.x = RFL(f.x); plo.y = RFL(f.y);
        phi.x = RFL(f.z); phi.y = RFL(f.w);
        xpair[ic][2 * j]     = plo;
        xpair[ic][2 * j + 1] = phi;
      }
    }
#pragma unroll
    for (int kx = 0; kx < 6; ++kx) {
#pragma unroll
      for (int ic = 0; ic < 3; ++ic) {
        f32x2 wv = wtc[(size_t)((ky * 6 + kx) * 3 + ic) * 1024];  // L2-hit 8B
#pragma unroll
        for (int q = 0; q < 27; ++q) {
          const int col = kx + q;               // compile-time after unroll
          f32x2 xp = xpair[ic][col >> 1];
          acc[q] = (col & 1) ? pk_fma_bhi(wv, xp, acc[q])
                             : pk_fma_blo(wv, xp, acc[q]);  // strict chain
        }
      }
    }
  }
  float* dstbase = conv + ((size_t)(bl * 27 + y) * 27) * 2048;
#pragma unroll
  for (int q = 0; q < 27; ++q) {
    dstbase[(size_t)q * 2048 + cpair]        = acc[q].x;
    dstbase[(size_t)q * 2048 + cpair + 1024] = acc[q].y;
  }
}

// ------- kernel 3: 4-pixel register-resident rank-819 select + byte mask ----
// UNCHANGED from round 9 (passing, bit-exact).
__global__ __launch_bounds__(256, 2) void net99_select(const float* __restrict__ conv,
                                                       const float* __restrict__ bias,
                                                       uint8_t* __restrict__ mskb, int b0) {
  const int bl = blockIdx.x / 183;
  const int g  = blockIdx.x % 183;
  const int p0 = 4 * g;
  const int npix = (g < 182) ? 4 : 1;     // 182*4=728, tail block: pixel 728
  const int nst  = 2 * npix;
  const int gb = b0 + bl;
  const int tid  = threadIdx.x;
  const int lane = tid & 63;
  const int wid  = tid >> 6;
  __shared__ uint32_t hist[8][256];       //  8 KB
  __shared__ float    cand[8][512];       // 16 KB
  __shared__ int      cnt[8];
  __shared__ int      sbin[8], sbelow[8];
  __shared__ float    skth[8];

  const float4* __restrict__ s0 =
      (const float4*)(conv + ((size_t)bl * 729 + p0) * 2048) + tid * 2;
  const float4* __restrict__ b4 = (const float4*)bias + tid * 2;
  float4 va[4][2];
#pragma unroll
  for (int k = 0; k < 4; ++k) {
    if (k < npix) { va[k][0] = s0[k * 512]; va[k][1] = s0[k * 512 + 1]; }
    else          { va[k][0] = float4{0,0,0,0}; va[k][1] = float4{0,0,0,0}; }
  }
  float4 ba = b4[0], bb = b4[1];

#pragma unroll
  for (int r = 0; r < 8; ++r) (&hist[0][0])[tid + 256 * r] = 0u;
  if (tid < 8) cnt[tid] = 0;

  float z[8][8];
  {
    float bv[8] = {ba.x, ba.y, ba.z, ba.w, bb.x, bb.y, bb.z, bb.w};
#pragma unroll
    for (int k = 0; k < 4; ++k) {
      float v[8] = {va[k][0].x, va[k][0].y, va[k][0].z, va[k][0].w,
                    va[k][1].x, va[k][1].y, va[k][1].z, va[k][1].w};
#pragma unroll
      for (int j = 0; j < 8; ++j) {
        z[2 * k][j]     = bv[j] - v[j];   // single f32 op, matches reference
        z[2 * k + 1][j] = bv[j] + v[j];
      }
    }
  }
  __syncthreads();                                  // hist zeros visible
#pragma unroll
  for (int s = 0; s < 8; ++s) {
    if (s < nst) {
#pragma unroll
      for (int j = 0; j < 8; ++j) atomicAdd(&hist[s][zbin256(z[s][j])], 1u);
    }
  }
  __syncthreads();
#pragma unroll
  for (int rep = 0; rep < 2; ++rep) {     // wave w scans streams w, w+4
    const int s = wid + 4 * rep;
    if (s < nst) {
      int h[4];
#pragma unroll
      for (int t = 0; t < 4; ++t) h[t] = (int)hist[s][lane * 4 + t];
      int loc = h[0] + h[1] + h[2] + h[3];
      int inc = loc;
#pragma unroll
      for (int off = 1; off < 64; off <<= 1) {
        int u = __shfl_up(inc, off);
        if (lane >= off) inc += u;
      }
      int pre = inc - loc;
      if (pre <= RANK_K && RANK_K < pre + loc) {    // exactly one lane
        int cum = pre;
#pragma unroll
        for (int t = 0; t < 4; ++t) {
          if (RANK_K < cum + h[t]) { sbin[s] = lane * 4 + t; sbelow[s] = cum; break; }
          cum += h[t];
        }
      }
    }
  }
  __syncthreads();
#pragma unroll
  for (int s = 0; s < 8; ++s) {                     // compact from registers
    if (s < nst) {
      const int tb = sbin[s];
#pragma unroll
      for (int j = 0; j < 8; ++j) {
        if (zbin256(z[s][j]) == tb) {
          int u = atomicAdd(&cnt[s], 1);
          if (u < 512) cand[s][u] = z[s][j];
        }
      }
    }
  }
  __syncthreads();
#pragma unroll
  for (int rep = 0; rep < 2; ++rep) {     // exact rank, wave w: streams w, w+4
    const int s = wid + 4 * rep;
    if (s < nst) {
      int cN = cnt[s] < 512 ? cnt[s] : 512;
      int rloc = RANK_K - sbelow[s];
      for (int ci = lane; ci < cN; ci += 64) {
        float v = cand[s][ci]; int rk = 0;
        for (int j = 0; j < cN; ++j) {
          float u = cand[s][j];
          rk += (u < v) || (u == v && j < ci);
        }
        if (rk == rloc) skth[s] = v;                // unique winning VALUE
      }
    }
  }
  __syncthreads();
#pragma unroll
  for (int k = 0; k < 4; ++k) {
    if (k < npix) {
      uint32_t m0 = 0u, m1 = 0u;
      const float k0 = skth[2 * k], k1 = skth[2 * k + 1];
#pragma unroll
      for (int j = 0; j < 8; ++j) {
        m0 |= (uint32_t)(z[2 * k][j] < k0) << j;
        m1 |= (uint32_t)(z[2 * k + 1][j] < k1) << j;
      }
      const size_t pix = (size_t)gb * 729 + p0 + k;
      mskb[pix * 256 + tid]                      = (uint8_t)m0;
      mskb[((size_t)64 * 729 + pix) * 256 + tid] = (uint8_t)m1;
    }
  }
}

// ------- kernel 4: bit-exact avg_pool(5,3,ceil) + adaptive(6), LDS-staged ---
__global__ __launch_bounds__(256) void net99_pool(const uint32_t* __restrict__ msk,
                                                  float* __restrict__ out) {
  __shared__ uint32_t stage[729 * 8];   // 23,328 B: full (s,b,cg) mask slice
  const int blk = blockIdx.x;           // 0..1023 = (sb, cg)
  const int cg  = blk & 7;
  const int sb  = blk >> 3;             // s*64 + b
  const int tid = threadIdx.x;
  const uint32_t* src = msk + (size_t)sb * 729 * 64 + cg * 8;
  for (int i = tid; i < 729 * 8; i += 256) {
    int p = i >> 3, w = i & 7;
    stage[i] = src[(size_t)p * 64 + w];
  }
  __syncthreads();
  const int lw = tid >> 5, sel = tid & 31;
  uint32_t rbm[27];
  for (int y = 0; y < 27; ++y) {
    uint32_t rb = 0;
#pragma unroll
    for (int xx = 0; xx < 27; ++xx)
      rb |= ((stage[(y * 27 + xx) * 8 + lw] >> sel) & 1u) << xx;
    rbm[y] = rb;
  }
  constexpr uint32_t WM[9] = {0x1Fu, 0xF8u, 0x7C0u, 0x3E00u, 0x1F000u,
                              0xF8000u, 0x7C0000u, 0x3E00000u, 0x7000000u};
  constexpr int CC[9]  = {5, 5, 5, 5, 5, 5, 5, 5, 3};
  constexpr int BW0[6] = {0, 1, 3, 4, 6, 7};
  constexpr int BW1[6] = {1, 2, 4, 5, 7, 8};
  const int s = sb >> 6, b = sb & 63, c = cg * 256 + tid;
  float* dst = out + (size_t)s * 4718592 + (size_t)(b * 2048 + c) * 36;
  for (int i = 0; i < 6; ++i) {
    float P[2][9];
#pragma unroll
    for (int t = 0; t < 2; ++t) {
      int r  = t ? BW1[i] : BW0[i];
      int y0 = 3 * r;
      int y1 = (y0 + 5 > 27) ? 27 : y0 + 5;
      int cr = y1 - y0;
      int pp[9];
#pragma unroll
      for (int cx = 0; cx < 9; ++cx) pp[cx] = 0;
      for (int yy = y0; yy < y1; ++yy) {
        uint32_t rb = rbm[yy];
#pragma unroll
        for (int cx = 0; cx < 9; ++cx) pp[cx] += __popc(rb & WM[cx]);
      }
#pragma unroll
      for (int cx = 0; cx < 9; ++cx)
        P[t][cx] = (float)pp[cx] / (float)(cr * CC[cx]);   // IEEE f32 div
    }
    float M[9];
#pragma unroll
    for (int cx = 0; cx < 9; ++cx) M[cx] = (P[0][cx] + P[1][cx]) * 0.5f;
#pragma unroll
    for (int j = 0; j < 6; ++j)
      dst[i * 6 + j] = (M[BW0[j]] + M[BW1[j]]) * 0.5f;
  }
}

extern "C" void kernel_launch(void* const* d_in, const int* in_sizes, int n_in,
                              void* d_out, int out_size, void* d_ws, size_t ws_size,
                              hipStream_t stream) {
  const float* x    = (const float*)d_in[0];
  const float* w    = (const float*)d_in[1];
  const float* bias = (const float*)d_in[2];
  float* out = (float*)d_out;
  uint8_t* ws = (uint8_t*)d_ws;

  const size_t WT_BYTES   = (size_t)108 * 1024 * 8;          //   884,736
  const size_t MASK_OFF   = WT_BYTES;
  const size_t MASK_BYTES = (size_t)2 * 64 * 729 * 64 * 4;   // 23,887,872
  const size_t CONV_OFF   = MASK_OFF + MASK_BYTES;           // 24,772,608
  const size_t PER_B      = (size_t)2048 * 729 * 4;          // 5,971,968 per batch

  f32x2*    wt4  = (f32x2*)ws;
  uint8_t*  mskb = (uint8_t*)(ws + MASK_OFF);
  uint32_t* msk  = (uint32_t*)(ws + MASK_OFF);
  float*    conv = (float*)(ws + CONV_OFF);

  size_t avail = ws_size > CONV_OFF ? ws_size - CONV_OFF : 0;
  int Bc = (int)(avail / PER_B);
  if (Bc < 1) Bc = 1;       // assumes ws_size >= ~31 MB
  if (Bc > 64) Bc = 64;

  hipLaunchKernelGGL(net99_wtrans, dim3((108 * 1024 + 255) / 256), dim3(256), 0, stream, w, wt4);
  for (int b0 = 0; b0 < 64; b0 += Bc) {
    int nb = (64 - b0 < Bc) ? (64 - b0) : Bc;
    hipLaunchKernelGGL(net99_conv, dim3(27, 4, nb), dim3(256), 0, stream, x, wt4, conv, b0);
    hipLaunchKernelGGL(net99_select, dim3(nb * 183), dim3(256), 0, stream, conv, bias, mskb, b0);
  }
  hipLaunchKernelGGL(net99_pool, dim3(1024), dim3(256), 0, stream, msk, out);
}

// Round 12
// 475.582 us; speedup vs baseline: 1.1302x; 1.0149x over previous
//
#include <hip/hip_runtime.h>
#include <cstdint>
#include <cstddef>

#define RANK_K 819            // kth = sorted[819] (820th smallest of 2048)
// conv: x[64,3,32,32] * w[2048,3,6,6] VALID -> [64,2048,27,27]

typedef __attribute__((ext_vector_type(2)))  float f32x2;
typedef __attribute__((ext_vector_type(16))) float f32x16;

// scalar load: 16 dwords straight into SGPRs (address is block-uniform)
__device__ __forceinline__ f32x16 sload16(const float* p) {
  f32x16 r;
  asm volatile("s_load_dwordx16 %0, %1, 0x0\n\ts_waitcnt lgkmcnt(0)"
               : "=s"(r) : "s"(p));
  return r;
}

// v_pk_fma_f32, src1 = SGPR PAIR (VOP3P sources are 64-bit; single SGPR is
// illegal). op_sel picks which half both lanes broadcast from.
// HW-validated bit-exact in round 10.
// blo: both result halves read the LO dword of the pair (even column).
__device__ __forceinline__ f32x2 pk_fma_blo(f32x2 a, f32x2 bs, f32x2 c) {
  f32x2 d;
  asm("v_pk_fma_f32 %0, %1, %2, %3 op_sel_hi:[1,0,1]"
      : "=v"(d) : "v"(a), "s"(bs), "v"(c));
  return d;
}
// bhi: both result halves read the HI dword of the pair (odd column).
__device__ __forceinline__ f32x2 pk_fma_bhi(f32x2 a, f32x2 bs, f32x2 c) {
  f32x2 d;
  asm("v_pk_fma_f32 %0, %1, %2, %3 op_sel:[0,1,0] op_sel_hi:[1,1,1]"
      : "=v"(d) : "v"(a), "s"(bs), "v"(c));
  return d;
}

__device__ __forceinline__ int zbin256(float z) {
  // 256 bins over [-8,8), width 1/16. Monotone partition; selection is exact
  // rank within bin, so binning never affects the kth VALUE.
  float t = (z + 8.0f) * 16.0f;
  t = t < 0.0f ? 0.0f : (t > 255.0f ? 255.0f : t);
  return (int)t;
}

// ------- kernel 1: weight pairs wt4[k][cc] = (w[cc][k], w[cc+1024][k]) ------
__global__ __launch_bounds__(256) void net99_wtrans(const float* __restrict__ w,
                                                    f32x2* __restrict__ wt4) {
  int idx = blockIdx.x * 256 + threadIdx.x;
  if (idx < 108 * 1024) {
    int k = idx / 1024, cc = idx % 1024;
    int ic = k % 3, sp = k / 3, ky = sp / 6, kx = sp % 6;
    int wo = ic * 36 + ky * 6 + kx;
    f32x2 t;
    t.x = w[cc * 108 + wo];
    t.y = w[(cc + 1024) * 108 + wo];
    wt4[idx] = t;
  }
}

// ------- kernel 2: f32 conv, col-streaming pk_fma, x via s_load -> SGPR -----
// Per output q the chain is still (ky -> kx -> ic) ascending: col m = q+kx
// sweeps ascending => kx ascending; ic innermost. Bit-exact.
__global__ __launch_bounds__(256, 4) void net99_conv(const float* __restrict__ x,
                                                     const f32x2* __restrict__ wt4,
                                                     float* __restrict__ conv, int b0) {
  const int y  = blockIdx.x;       // 0..26
  const int ct = blockIdx.y;       // 0..3 (512-channel tiles)
  const int bl = blockIdx.z;       // local batch
  const int b  = b0 + bl;
  const int tid = threadIdx.x;
  const int cpair = ct * 256 + tid;            // channels cpair, cpair+1024
  const f32x2* wtc = wt4 + cpair;
  f32x2 acc[27];
#pragma unroll
  for (int q = 0; q < 27; ++q) acc[q] = (f32x2)(0.0f);
#pragma unroll 1
  for (int ky = 0; ky < 6; ++ky) {   // runtime loop: code size + SGPR window
    const float* r0 = x + ((b * 3 + 0) * 32 + (y + ky)) * 32;
    const float* r1 = x + ((b * 3 + 1) * 32 + (y + ky)) * 32;
    const float* r2 = x + ((b * 3 + 2) * 32 + (y + ky)) * 32;
    // this ky's 18 weight pairs (coalesced dwordx2, L2-resident)
    f32x2 wv[6][3];
#pragma unroll
    for (int kx = 0; kx < 6; ++kx)
#pragma unroll
      for (int ic = 0; ic < 3; ++ic)
        wv[kx][ic] = wtc[(size_t)((ky * 6 + kx) * 3 + ic) * 1024];
    // half A: cols 0..15 in SGPRs
    {
      f32x16 a0 = sload16(r0), a1 = sload16(r1), a2 = sload16(r2);
#pragma unroll
      for (int m = 0; m < 16; ++m) {
        f32x2 p0, p1, p2;                       // pair holding column m
        p0.x = a0[(m >> 1) * 2]; p0.y = a0[(m >> 1) * 2 + 1];
        p1.x = a1[(m >> 1) * 2]; p1.y = a1[(m >> 1) * 2 + 1];
        p2.x = a2[(m >> 1) * 2]; p2.y = a2[(m >> 1) * 2 + 1];
#pragma unroll
        for (int kx = 0; kx < 6; ++kx) {
          if (kx <= m) {                 // q = m-kx in [0,26] guaranteed
            const int q = m - kx;
            if (m & 1) {
              acc[q] = pk_fma_bhi(wv[kx][0], p0, acc[q]);
              acc[q] = pk_fma_bhi(wv[kx][1], p1, acc[q]);
              acc[q] = pk_fma_bhi(wv[kx][2], p2, acc[q]);
            } else {
              acc[q] = pk_fma_blo(wv[kx][0], p0, acc[q]);
              acc[q] = pk_fma_blo(wv[kx][1], p1, acc[q]);
              acc[q] = pk_fma_blo(wv[kx][2], p2, acc[q]);
            }
          }
        }
      }
    }
    // half B: cols 16..31 in SGPRs
    {
      f32x16 c0 = sload16(r0 + 16), c1 = sload16(r1 + 16), c2 = sload16(r2 + 16);
#pragma unroll
      for (int m = 16; m < 32; ++m) {
        const int mm = m - 16;
        f32x2 p0, p1, p2;
        p0.x = c0[(mm >> 1) * 2]; p0.y = c0[(mm >> 1) * 2 + 1];
        p1.x = c1[(mm >> 1) * 2]; p1.y = c1[(mm >> 1) * 2 + 1];
        p2.x = c2[(mm >> 1) * 2]; p2.y = c2[(mm >> 1) * 2 + 1];
#pragma unroll
        for (int kx = 0; kx < 6; ++kx) {
          const int q = m - kx;
          if (q <= 26) {                 // kx <= 5 <= m always
            if (m & 1) {
              acc[q] = pk_fma_bhi(wv[kx][0], p0, acc[q]);
              acc[q] = pk_fma_bhi(wv[kx][1], p1, acc[q]);
              acc[q] = pk_fma_bhi(wv[kx][2], p2, acc[q]);
            } else {
              acc[q] = pk_fma_blo(wv[kx][0], p0, acc[q]);
              acc[q] = pk_fma_blo(wv[kx][1], p1, acc[q]);
              acc[q] = pk_fma_blo(wv[kx][2], p2, acc[q]);
            }
          }
        }
      }
    }
  }
  float* dstbase = conv + ((size_t)(bl * 27 + y) * 27) * 2048;
#pragma unroll
  for (int q = 0; q < 27; ++q) {
    dstbase[(size_t)q * 2048 + cpair]        = acc[q].x;
    dstbase[(size_t)q * 2048 + cpair + 1024] = acc[q].y;
  }
}

// ------- kernel 3: 4-pixel register-resident rank-819 select + byte mask ----
// UNCHANGED (passing, bit-exact).
__global__ __launch_bounds__(256, 2) void net99_select(const float* __restrict__ conv,
                                                       const float* __restrict__ bias,
                                                       uint8_t* __restrict__ mskb, int b0) {
  const int bl = blockIdx.x / 183;
  const int g  = blockIdx.x % 183;
  const int p0 = 4 * g;
  const int npix = (g < 182) ? 4 : 1;     // 182*4=728, tail block: pixel 728
  const int nst  = 2 * npix;
  const int gb = b0 + bl;
  const int tid  = threadIdx.x;
  const int lane = tid & 63;
  const int wid  = tid >> 6;
  __shared__ uint32_t hist[8][256];       //  8 KB
  __shared__ float    cand[8][512];       // 16 KB
  __shared__ int      cnt[8];
  __shared__ int      sbin[8], sbelow[8];
  __shared__ float    skth[8];

  const float4* __restrict__ s0 =
      (const float4*)(conv + ((size_t)bl * 729 + p0) * 2048) + tid * 2;
  const float4* __restrict__ b4 = (const float4*)bias + tid * 2;
  float4 va[4][2];
#pragma unroll
  for (int k = 0; k < 4; ++k) {
    if (k < npix) { va[k][0] = s0[k * 512]; va[k][1] = s0[k * 512 + 1]; }
    else          { va[k][0] = float4{0,0,0,0}; va[k][1] = float4{0,0,0,0}; }
  }
  float4 ba = b4[0], bb = b4[1];

#pragma unroll
  for (int r = 0; r < 8; ++r) (&hist[0][0])[tid + 256 * r] = 0u;
  if (tid < 8) cnt[tid] = 0;

  float z[8][8];
  {
    float bv[8] = {ba.x, ba.y, ba.z, ba.w, bb.x, bb.y, bb.z, bb.w};
#pragma unroll
    for (int k = 0; k < 4; ++k) {
      float v[8] = {va[k][0].x, va[k][0].y, va[k][0].z, va[k][0].w,
                    va[k][1].x, va[k][1].y, va[k][1].z, va[k][1].w};
#pragma unroll
      for (int j = 0; j < 8; ++j) {
        z[2 * k][j]     = bv[j] - v[j];   // single f32 op, matches reference
        z[2 * k + 1][j] = bv[j] + v[j];
      }
    }
  }
  __syncthreads();                                  // hist zeros visible
#pragma unroll
  for (int s = 0; s < 8; ++s) {
    if (s < nst) {
#pragma unroll
      for (int j = 0; j < 8; ++j) atomicAdd(&hist[s][zbin256(z[s][j])], 1u);
    }
  }
  __syncthreads();
#pragma unroll
  for (int rep = 0; rep < 2; ++rep) {     // wave w scans streams w, w+4
    const int s = wid + 4 * rep;
    if (s < nst) {
      int h[4];
#pragma unroll
      for (int t = 0; t < 4; ++t) h[t] = (int)hist[s][lane * 4 + t];
      int loc = h[0] + h[1] + h[2] + h[3];
      int inc = loc;
#pragma unroll
      for (int off = 1; off < 64; off <<= 1) {
        int u = __shfl_up(inc, off);
        if (lane >= off) inc += u;
      }
      int pre = inc - loc;
      if (pre <= RANK_K && RANK_K < pre + loc) {    // exactly one lane
        int cum = pre;
#pragma unroll
        for (int t = 0; t < 4; ++t) {
          if (RANK_K < cum + h[t]) { sbin[s] = lane * 4 + t; sbelow[s] = cum; break; }
          cum += h[t];
        }
      }
    }
  }
  __syncthreads();
#pragma unroll
  for (int s = 0; s < 8; ++s) {                     // compact from registers
    if (s < nst) {
      const int tb = sbin[s];
#pragma unroll
      for (int j = 0; j < 8; ++j) {
        if (zbin256(z[s][j]) == tb) {
          int u = atomicAdd(&cnt[s], 1);
          if (u < 512) cand[s][u] = z[s][j];
        }
      }
    }
  }
  __syncthreads();
#pragma unroll
  for (int rep = 0; rep < 2; ++rep) {     // exact rank, wave w: streams w, w+4
    const int s = wid + 4 * rep;
    if (s < nst) {
      int cN = cnt[s] < 512 ? cnt[s] : 512;
      int rloc = RANK_K - sbelow[s];
      for (int ci = lane; ci < cN; ci += 64) {
        float v = cand[s][ci]; int rk = 0;
        for (int j = 0; j < cN; ++j) {
          float u = cand[s][j];
          rk += (u < v) || (u == v && j < ci);
        }
        if (rk == rloc) skth[s] = v;                // unique winning VALUE
      }
    }
  }
  __syncthreads();
#pragma unroll
  for (int k = 0; k < 4; ++k) {
    if (k < npix) {
      uint32_t m0 = 0u, m1 = 0u;
      const float k0 = skth[2 * k], k1 = skth[2 * k + 1];
#pragma unroll
      for (int j = 0; j < 8; ++j) {
        m0 |= (uint32_t)(z[2 * k][j] < k0) << j;
        m1 |= (uint32_t)(z[2 * k + 1][j] < k1) << j;
      }
      const size_t pix = (size_t)gb * 729 + p0 + k;
      mskb[pix * 256 + tid]                      = (uint8_t)m0;
      mskb[((size_t)64 * 729 + pix) * 256 + tid] = (uint8_t)m1;
    }
  }
}

// ------- kernel 4: bit-exact avg_pool(5,3,ceil) + adaptive(6), LDS-staged ---
__global__ __launch_bounds__(256) void net99_pool(const uint32_t* __restrict__ msk,
                                                  float* __restrict__ out) {
  __shared__ uint32_t stage[729 * 8];   // 23,328 B: full (s,b,cg) mask slice
  const int blk = blockIdx.x;           // 0..1023 = (sb, cg)
  const int cg  = blk & 7;
  const int sb  = blk >> 3;             // s*64 + b
  const int tid = threadIdx.x;
  const uint32_t* src = msk + (size_t)sb * 729 * 64 + cg * 8;
  for (int i = tid; i < 729 * 8; i += 256) {
    int p = i >> 3, w = i & 7;
    stage[i] = src[(size_t)p * 64 + w];
  }
  __syncthreads();
  const int lw = tid >> 5, sel = tid & 31;
  uint32_t rbm[27];
  for (int y = 0; y < 27; ++y) {
    uint32_t rb = 0;
#pragma unroll
    for (int xx = 0; xx < 27; ++xx)
      rb |= ((stage[(y * 27 + xx) * 8 + lw] >> sel) & 1u) << xx;
    rbm[y] = rb;
  }
  constexpr uint32_t WM[9] = {0x1Fu, 0xF8u, 0x7C0u, 0x3E00u, 0x1F000u,
                              0xF8000u, 0x7C0000u, 0x3E00000u, 0x7000000u};
  constexpr int CC[9]  = {5, 5, 5, 5, 5, 5, 5, 5, 3};
  constexpr int BW0[6] = {0, 1, 3, 4, 6, 7};
  constexpr int BW1[6] = {1, 2, 4, 5, 7, 8};
  const int s = sb >> 6, b = sb & 63, c = cg * 256 + tid;
  float* dst = out + (size_t)s * 4718592 + (size_t)(b * 2048 + c) * 36;
  for (int i = 0; i < 6; ++i) {
    float P[2][9];
#pragma unroll
    for (int t = 0; t < 2; ++t) {
      int r  = t ? BW1[i] : BW0[i];
      int y0 = 3 * r;
      int y1 = (y0 + 5 > 27) ? 27 : y0 + 5;
      int cr = y1 - y0;
      int pp[9];
#pragma unroll
      for (int cx = 0; cx < 9; ++cx) pp[cx] = 0;
      for (int yy = y0; yy < y1; ++yy) {
        uint32_t rb = rbm[yy];
#pragma unroll
        for (int cx = 0; cx < 9; ++cx) pp[cx] += __popc(rb & WM[cx]);
      }
#pragma unroll
      for (int cx = 0; cx < 9; ++cx)
        P[t][cx] = (float)pp[cx] / (float)(cr * CC[cx]);   // IEEE f32 div
    }
    float M[9];
#pragma unroll
    for (int cx = 0; cx < 9; ++cx) M[cx] = (P[0][cx] + P[1][cx]) * 0.5f;
#pragma unroll
    for (int j = 0; j < 6; ++j)
      dst[i * 6 + j] = (M[BW0[j]] + M[BW1[j]]) * 0.5f;
  }
}

extern "C" void kernel_launch(void* const* d_in, const int* in_sizes, int n_in,
                              void* d_out, int out_size, void* d_ws, size_t ws_size,
                              hipStream_t stream) {
  const float* x    = (const float*)d_in[0];
  const float* w    = (const float*)d_in[1];
  const float* bias = (const float*)d_in[2];
  float* out = (float*)d_out;
  uint8_t* ws = (uint8_t*)d_ws;

  const size_t WT_BYTES   = (size_t)108 * 1024 * 8;          //   884,736
  const size_t MASK_OFF   = WT_BYTES;
  const size_t MASK_BYTES = (size_t)2 * 64 * 729 * 64 * 4;   // 23,887,872
  const size_t CONV_OFF   = MASK_OFF + MASK_BYTES;           // 24,772,608
  const size_t PER_B      = (size_t)2048 * 729 * 4;          // 5,971,968 per batch

  f32x2*    wt4  = (f32x2*)ws;
  uint8_t*  mskb = (uint8_t*)(ws + MASK_OFF);
  uint32_t* msk  = (uint32_t*)(ws + MASK_OFF);
  float*    conv = (float*)(ws + CONV_OFF);

  size_t avail = ws_size > CONV_OFF ? ws_size - CONV_OFF : 0;
  int Bc = (int)(avail / PER_B);
  if (Bc < 1) Bc = 1;       // assumes ws_size >= ~31 MB
  if (Bc > 64) Bc = 64;

  hipLaunchKernelGGL(net99_wtrans, dim3((108 * 1024 + 255) / 256), dim3(256), 0, stream, w, wt4);
  for (int b0 = 0; b0 < 64; b0 += Bc) {
    int nb = (64 - b0 < Bc) ? (64 - b0) : Bc;
    hipLaunchKernelGGL(net99_conv, dim3(27, 4, nb), dim3(256), 0, stream, x, wt4, conv, b0);
    hipLaunchKernelGGL(net99_select, dim3(nb * 183), dim3(256), 0, stream, conv, bias, mskb, b0);
  }
  hipLaunchKernelGGL(net99_pool, dim3(1024), dim3(256), 0, stream, msk, out);
}